// Round 6
// baseline (188.464 us; speedup 1.0000x reference)
//
#include <hip/hip_runtime.h>
#include <stdint.h>

#define M_TOK 8192
#define N_OUT 4096
#define K_IN  4096

#define BM 256
#define BN 256
#define BK 128                 // bytes == elements (i8)
#define NT (K_IN / BK)         // 32 K-tiles
#define NIT (NT / 2)           // 16 iterations, 2 K-tiles each

typedef __attribute__((ext_vector_type(4))) int i32x4;

// ---------------------------------------------------------------------------
// Pass 1 (fused): blocks [0, 2048): per-token symmetric quant of x -> i8 + sx.
//                 blocks [2048, 3072): pack weight_q (i32) -> i8 (exact).
// ---------------------------------------------------------------------------
__global__ void prep_kernel(const float* __restrict__ x,
                            const int* __restrict__ wq,
                            char* __restrict__ A8,
                            float* __restrict__ sx,
                            char* __restrict__ B8) {
  if (blockIdx.x < M_TOK / 4) {
    int row = blockIdx.x * 4 + (threadIdx.x >> 6);
    int lane = threadIdx.x & 63;
    const float* xr = x + (size_t)row * K_IN;

    float4 v[4][4];
    float mx = 0.f;
#pragma unroll
    for (int c = 0; c < 4; ++c) {
      int base = c * 1024 + lane * 16;
#pragma unroll
      for (int j = 0; j < 4; ++j) {
        v[c][j] = *reinterpret_cast<const float4*>(xr + base + j * 4);
        mx = fmaxf(mx, fmaxf(fmaxf(fabsf(v[c][j].x), fabsf(v[c][j].y)),
                             fmaxf(fabsf(v[c][j].z), fabsf(v[c][j].w))));
      }
    }
#pragma unroll
    for (int m = 32; m > 0; m >>= 1) mx = fmaxf(mx, __shfl_xor(mx, m));

    float inv = (mx > 0.f) ? (127.0f / mx) : 0.f;
    if (lane == 0) sx[row] = (mx > 0.f) ? (mx / 127.0f) : 1.0f;

#pragma unroll
    for (int c = 0; c < 4; ++c) {
      int qi[16];
#pragma unroll
      for (int j = 0; j < 4; ++j) {
        qi[j * 4 + 0] = __float2int_rn(v[c][j].x * inv);
        qi[j * 4 + 1] = __float2int_rn(v[c][j].y * inv);
        qi[j * 4 + 2] = __float2int_rn(v[c][j].z * inv);
        qi[j * 4 + 3] = __float2int_rn(v[c][j].w * inv);
      }
      int4 p;
      int* pp = (int*)&p;
#pragma unroll
      for (int w = 0; w < 4; ++w) {
        int a0 = min(127, max(-127, qi[w * 4 + 0])) & 0xff;
        int a1 = min(127, max(-127, qi[w * 4 + 1])) & 0xff;
        int a2 = min(127, max(-127, qi[w * 4 + 2])) & 0xff;
        int a3 = min(127, max(-127, qi[w * 4 + 3])) & 0xff;
        pp[w] = a0 | (a1 << 8) | (a2 << 16) | (a3 << 24);
      }
      *reinterpret_cast<int4*>(A8 + (size_t)row * K_IN + c * 1024 + lane * 16) = p;
    }
  } else {
    const int total = (N_OUT * K_IN) / 16;   // 1,048,576 units of 16 i8
    int idx = (blockIdx.x - M_TOK / 4) * blockDim.x + threadIdx.x;
    for (int i = idx; i < total; i += 1024 * 256) {
      int4 p;
      int* pp = (int*)&p;
#pragma unroll
      for (int w = 0; w < 4; ++w) {
        int4 s = reinterpret_cast<const int4*>(wq)[i * 4 + w];
        pp[w] = (s.x & 0xff) | ((s.y & 0xff) << 8) | ((s.z & 0xff) << 16) |
                ((s.w & 0xff) << 24);
      }
      reinterpret_cast<int4*>(B8)[i] = p;
    }
  }
}

// ---------------------------------------------------------------------------
// Pass 2: 256x256 i8 MFMA GEMM, 4-phase schedule (merged from the verified
// 8-phase round-3 kernel): 32 MFMA per phase, half the barriers.
// LDS 128 KiB: A(buf,h)=buf*65536+h*16384; B(buf,h)=+32768. 128-B rows =
// 8 slots of 16 B; phys_slot = log_slot ^ (row&7); linear LDS dest +
// inverse-swizzled global source (rule #21).
// Stage-placement rule (race-free): a half-tile stage issues only in a phase
// strictly AFTER the phase containing its last reader (full barrier between
// reader lgkm-drain and stage issue).
//   Q1 reads buf0{A-h0,B-h0,B-h1}; stages b1-Ah1(kt1)      [readers: prev Q4]
//   Q2 reads buf0{A-h1};           stages b0-{Ah0,Bh0,Bh1}(kt2) [readers: Q1]
//       vmcnt(6): drains prevQ4(6)+Q1(2) = buf1 tile complete
//   Q3 reads buf1{A-h0,B-h0,B-h1}; stages b0-Ah1(kt2)      [reader: Q2]
//   Q4 reads buf1{A-h1};           stages b1-{Ah0,Bh0,Bh1}(kt3) [readers: Q3]
//       vmcnt(6): drains Q2(6)+Q3(2) = buf0 tile complete
// ---------------------------------------------------------------------------
#define GLOAD_LDS16(gptr, lptr)                                               \
  __builtin_amdgcn_global_load_lds(                                           \
      (const __attribute__((address_space(1))) void*)(gptr),                  \
      (__attribute__((address_space(3))) void*)(lptr), 16, 0, 0)

#define WAITCNT(s) asm volatile("s_waitcnt " s ::: "memory")

#define LDSA(buf, mh, fm, kk)                                                 \
  (*reinterpret_cast<const i32x4*>(                                           \
      lds + (buf)*65536 + (mh)*16384 + aRow + (fm)*2048 +                     \
      (((((kk)*4) | sBase) ^ sXor) << 4)))
#define LDSB(buf, nh, fn, kk)                                                 \
  (*reinterpret_cast<const i32x4*>(                                           \
      lds + (buf)*65536 + 32768 + (nh)*16384 + bRow + (fn)*2048 +             \
      (((((kk)*4) | sBase) ^ sXor) << 4)))

#define STAGE_A(buf, h, kt)                                                   \
  do {                                                                        \
    const char* _s = stA + (size_t)(h) * 128 * K_IN + (kt) * BK;              \
    GLOAD_LDS16(_s, lds + (buf)*65536 + (h)*16384 + ldsW0);                   \
    GLOAD_LDS16(_s + (size_t)64 * K_IN,                                       \
                lds + (buf)*65536 + (h)*16384 + 8192 + ldsW0);                \
  } while (0)
#define STAGE_B(buf, h, kt)                                                   \
  do {                                                                        \
    const char* _s = stB + (size_t)(h) * 128 * K_IN + (kt) * BK;              \
    GLOAD_LDS16(_s, lds + (buf)*65536 + 32768 + (h)*16384 + ldsW0);           \
    GLOAD_LDS16(_s + (size_t)64 * K_IN,                                       \
                lds + (buf)*65536 + 32768 + (h)*16384 + 8192 + ldsW0);        \
  } while (0)

#define MFMA16(mh, nh, BR)                                                    \
  do {                                                                        \
    _Pragma("unroll") for (int fm = 0; fm < 4; ++fm)                          \
    _Pragma("unroll") for (int fn = 0; fn < 2; ++fn) {                        \
      acc[mh][nh][fm][fn] = __builtin_amdgcn_mfma_i32_16x16x64_i8(            \
          aR[fm][0], BR[fn][0], acc[mh][nh][fm][fn], 0, 0, 0);                \
      acc[mh][nh][fm][fn] = __builtin_amdgcn_mfma_i32_16x16x64_i8(            \
          aR[fm][1], BR[fn][1], acc[mh][nh][fm][fn], 0, 0, 0);                \
    }                                                                         \
  } while (0)

#define PH_MID()                                                              \
  __builtin_amdgcn_s_barrier();                                               \
  WAITCNT("lgkmcnt(0)");                                                      \
  __builtin_amdgcn_sched_barrier(0);                                          \
  __builtin_amdgcn_s_setprio(1)

#define PH_END()                                                              \
  __builtin_amdgcn_s_setprio(0);                                              \
  __builtin_amdgcn_s_barrier();                                               \
  __builtin_amdgcn_sched_barrier(0)

#define PH_END_VM()                                                           \
  __builtin_amdgcn_s_setprio(0);                                              \
  WAITCNT("vmcnt(6)");                                                        \
  __builtin_amdgcn_sched_barrier(0);                                          \
  __builtin_amdgcn_s_barrier();                                               \
  __builtin_amdgcn_sched_barrier(0)

__global__ __launch_bounds__(512, 2) void gemm_4ph_i8(
    const char* __restrict__ A,        // [M][K] i8
    const char* __restrict__ B,        // [N][K] i8
    const float* __restrict__ sx,      // [M] per-row x scales
    const float* __restrict__ scales,  // [N]
    const float* __restrict__ bias,    // [N]
    float* __restrict__ out) {         // [M][N] f32
  __shared__ __align__(1024) char lds[131072];

  int bid = blockIdx.x;
  int swz = (bid & 7) * (512 / 8) + (bid >> 3);   // bijective, 512 % 8 == 0
  int bx = swz & 15;   // N tiles: 16
  int by = swz >> 4;   // M tiles: 32

  int tid = threadIdx.x;
  int lane = tid & 63;
  int wid = tid >> 6;
  int wm = wid >> 2;    // 0..1
  int wn = wid & 3;     // 0..3

  int aRow = (wm * 64 + (lane & 15)) * 128;   // bytes within A half
  int bRow = (wn * 32 + (lane & 15)) * 128;   // bytes within B half
  int sBase = lane >> 4;                      // 0..3
  int sXor = lane & 7;

  const char* stA = A + (size_t)(by * BM + wid * 8 + (lane >> 3)) * K_IN +
                    ((lane & 7) ^ (lane >> 3)) * 16;
  const char* stB = B + (size_t)(bx * BN + wid * 8 + (lane >> 3)) * K_IN +
                    ((lane & 7) ^ (lane >> 3)) * 16;
  int ldsW0 = wid * 1024;

  i32x4 acc[2][2][4][2] = {};   // [mh][nh][fm][fn], i32
  i32x4 aR[4][2];               // A frags [fm][kk] (current m-half)
  i32x4 bR0[2][2], bR1[2][2];   // B frags [fn][kk] for nh=0 / nh=1

  // ---- prologue: buf0 = tile0 full (8 loads); buf1 = tile1 {A-h0,B-h0,B-h1}
  // (6 loads). vmcnt(6) drains the 8 oldest = buf0 complete.
  STAGE_A(0, 0, 0); STAGE_A(0, 1, 0); STAGE_B(0, 0, 0); STAGE_B(0, 1, 0);
  STAGE_A(1, 0, 1); STAGE_B(1, 0, 1); STAGE_B(1, 1, 1);
  WAITCNT("vmcnt(6)");
  __builtin_amdgcn_s_barrier();
  __builtin_amdgcn_sched_barrier(0);

#pragma unroll 1
  for (int it = 0; it < NIT; ++it) {
    int kt1 = 2 * it + 1;
    int kt2 = (2 * it + 2) & (NT - 1);
    int kt3 = (2 * it + 3) & (NT - 1);

    // Q1: tile 2it (buf0), m-half 0, both n-halves; stage b1-Ah1(kt1)
#pragma unroll
    for (int fm = 0; fm < 4; ++fm) { aR[fm][0] = LDSA(0, 0, fm, 0); aR[fm][1] = LDSA(0, 0, fm, 1); }
#pragma unroll
    for (int fn = 0; fn < 2; ++fn) { bR0[fn][0] = LDSB(0, 0, fn, 0); bR0[fn][1] = LDSB(0, 0, fn, 1); }
#pragma unroll
    for (int fn = 0; fn < 2; ++fn) { bR1[fn][0] = LDSB(0, 1, fn, 0); bR1[fn][1] = LDSB(0, 1, fn, 1); }
    STAGE_A(1, 1, kt1);
    WAITCNT("lgkmcnt(8)");
    PH_MID();
    MFMA16(0, 0, bR0);
    MFMA16(0, 1, bR1);
    PH_END();

    // Q2: tile 2it (buf0), m-half 1; stage b0-{Ah0,Bh0,Bh1}(kt2); vmcnt(6)
#pragma unroll
    for (int fm = 0; fm < 4; ++fm) { aR[fm][0] = LDSA(0, 1, fm, 0); aR[fm][1] = LDSA(0, 1, fm, 1); }
    STAGE_A(0, 0, kt2); STAGE_B(0, 0, kt2); STAGE_B(0, 1, kt2);
    PH_MID();
    MFMA16(1, 0, bR0);
    MFMA16(1, 1, bR1);
    PH_END_VM();

    // Q3: tile 2it+1 (buf1), m-half 0; stage b0-Ah1(kt2)
#pragma unroll
    for (int fm = 0; fm < 4; ++fm) { aR[fm][0] = LDSA(1, 0, fm, 0); aR[fm][1] = LDSA(1, 0, fm, 1); }
#pragma unroll
    for (int fn = 0; fn < 2; ++fn) { bR0[fn][0] = LDSB(1, 0, fn, 0); bR0[fn][1] = LDSB(1, 0, fn, 1); }
#pragma unroll
    for (int fn = 0; fn < 2; ++fn) { bR1[fn][0] = LDSB(1, 1, fn, 0); bR1[fn][1] = LDSB(1, 1, fn, 1); }
    STAGE_A(0, 1, kt2);
    WAITCNT("lgkmcnt(8)");
    PH_MID();
    MFMA16(0, 0, bR0);
    MFMA16(0, 1, bR1);
    PH_END();

    // Q4: tile 2it+1 (buf1), m-half 1; stage b1-{Ah0,Bh0,Bh1}(kt3); vmcnt(6)
#pragma unroll
    for (int fm = 0; fm < 4; ++fm) { aR[fm][0] = LDSA(1, 1, fm, 0); aR[fm][1] = LDSA(1, 1, fm, 1); }
    STAGE_A(1, 0, kt3); STAGE_B(1, 0, kt3); STAGE_B(1, 1, kt3);
    PH_MID();
    MFMA16(1, 0, bR0);
    MFMA16(1, 1, bR1);
    PH_END_VM();
  }

  // ---- epilogue: out = acc * (sx[row] * scales[col]) + bias[col] ----
  // C/D (shape-determined): col = lane&15, row = (lane>>4)*4 + reg
  float sxv[2][4][4];
#pragma unroll
  for (int mh = 0; mh < 2; ++mh)
#pragma unroll
    for (int fm = 0; fm < 4; ++fm) {
      int row0 = by * BM + mh * 128 + wm * 64 + fm * 16 + (lane >> 4) * 4;
#pragma unroll
      for (int r = 0; r < 4; ++r) sxv[mh][fm][r] = sx[row0 + r];
    }

#pragma unroll
  for (int nh = 0; nh < 2; ++nh)
#pragma unroll
    for (int fn = 0; fn < 2; ++fn) {
      int col = bx * BN + nh * 128 + wn * 32 + fn * 16 + (lane & 15);
      float so = scales[col];
      float bv = bias[col];
#pragma unroll
      for (int mh = 0; mh < 2; ++mh)
#pragma unroll
        for (int fm = 0; fm < 4; ++fm) {
          int row0 = by * BM + mh * 128 + wm * 64 + fm * 16 + (lane >> 4) * 4;
          i32x4 v = acc[mh][nh][fm][fn];
#pragma unroll
          for (int r = 0; r < 4; ++r)
            out[(size_t)(row0 + r) * N_OUT + col] =
                (float)v[r] * (sxv[mh][fm][r] * so) + bv;
        }
    }
}

// ---------------------------------------------------------------------------
// Fallback (tiny ws): simple fp32 LDS-tiled GEMM (correct, slow).
// ---------------------------------------------------------------------------
__global__ void fallback_gemm(const float* __restrict__ x,
                              const int* __restrict__ wq,
                              const float* __restrict__ scales,
                              const float* __restrict__ bias,
                              float* __restrict__ out) {
  __shared__ float xs[64][33];
  __shared__ float ws_[64][33];
  int tx = threadIdx.x & 15;
  int ty = threadIdx.x >> 4;
  int brow = blockIdx.y * 64, bcol = blockIdx.x * 64;
  float acc[4][4] = {};
  for (int k0 = 0; k0 < K_IN; k0 += 32) {
    for (int i = threadIdx.x; i < 64 * 32; i += 256) {
      int r = i >> 5, c = i & 31;
      xs[r][c] = x[(size_t)(brow + r) * K_IN + k0 + c];
      ws_[r][c] = (float)wq[(size_t)(bcol + r) * K_IN + k0 + c];
    }
    __syncthreads();
#pragma unroll 8
    for (int k = 0; k < 32; ++k) {
      float xv[4], wv[4];
#pragma unroll
      for (int i = 0; i < 4; ++i) xv[i] = xs[ty * 4 + i][k];
#pragma unroll
      for (int j = 0; j < 4; ++j) wv[j] = ws_[tx * 4 + j][k];
#pragma unroll
      for (int i = 0; i < 4; ++i)
#pragma unroll
        for (int j = 0; j < 4; ++j) acc[i][j] += xv[i] * wv[j];
    }
    __syncthreads();
  }
#pragma unroll
  for (int i = 0; i < 4; ++i)
#pragma unroll
    for (int j = 0; j < 4; ++j) {
      int o = bcol + tx * 4 + j;
      out[(size_t)(brow + ty * 4 + i) * N_OUT + o] = acc[i][j] * scales[o] + bias[o];
    }
}

extern "C" void kernel_launch(void* const* d_in, const int* in_sizes, int n_in,
                              void* d_out, int out_size, void* d_ws, size_t ws_size,
                              hipStream_t stream) {
  const float* x = (const float*)d_in[0];
  const int* wq = (const int*)d_in[1];
  const float* scales = (const float*)d_in[2];
  const float* bias = (const float*)d_in[3];
  float* out = (float*)d_out;

  const size_t offB = (size_t)M_TOK * K_IN;            // 32 MiB (A8)
  const size_t offS = offB + (size_t)N_OUT * K_IN;     // +16 MiB (B8)
  const size_t need = offS + (size_t)M_TOK * 4;        // +32 KiB (sx)

  if (ws_size >= need) {
    char* A8 = (char*)d_ws;
    char* B8 = (char*)d_ws + offB;
    float* sx = (float*)((char*)d_ws + offS);
    prep_kernel<<<M_TOK / 4 + 1024, 256, 0, stream>>>(x, wq, A8, sx, B8);
    gemm_4ph_i8<<<(M_TOK / BM) * (N_OUT / BN), 512, 0, stream>>>(
        A8, B8, sx, scales, bias, out);
  } else {
    dim3 grid(N_OUT / 64, M_TOK / 64);
    fallback_gemm<<<grid, 256, 0, stream>>>(x, wq, scales, bias, out);
  }
}

// Round 7
// 184.387 us; speedup vs baseline: 1.0221x; 1.0221x over previous
//
#include <hip/hip_runtime.h>
#include <stdint.h>

#define M_TOK 8192
#define N_OUT 4096
#define K_IN  4096

#define BM 256
#define BN 256
#define BK 128                 // bytes == elements (i8)
#define NT (K_IN / BK)         // 32 K-tiles
#define NIT (NT / 2)           // 16 iterations, 2 K-tiles each

typedef __attribute__((ext_vector_type(4))) int i32x4;

// ---------------------------------------------------------------------------
// Pass 1 (fused): blocks [0, 2048): per-token symmetric quant of x -> i8 + sx.
//                 blocks [2048, 4096): pack weight_q (i32) -> i8 (exact).
// ---------------------------------------------------------------------------
__global__ void prep_kernel(const float* __restrict__ x,
                            const int* __restrict__ wq,
                            char* __restrict__ A8,
                            float* __restrict__ sx,
                            char* __restrict__ B8) {
  if (blockIdx.x < M_TOK / 4) {
    int row = blockIdx.x * 4 + (threadIdx.x >> 6);
    int lane = threadIdx.x & 63;
    const float* xr = x + (size_t)row * K_IN;

    float4 v[4][4];
    float mx = 0.f;
#pragma unroll
    for (int c = 0; c < 4; ++c) {
      int base = c * 1024 + lane * 16;
#pragma unroll
      for (int j = 0; j < 4; ++j) {
        v[c][j] = *reinterpret_cast<const float4*>(xr + base + j * 4);
        mx = fmaxf(mx, fmaxf(fmaxf(fabsf(v[c][j].x), fabsf(v[c][j].y)),
                             fmaxf(fabsf(v[c][j].z), fabsf(v[c][j].w))));
      }
    }
#pragma unroll
    for (int m = 32; m > 0; m >>= 1) mx = fmaxf(mx, __shfl_xor(mx, m));

    float inv = (mx > 0.f) ? (127.0f / mx) : 0.f;
    if (lane == 0) sx[row] = (mx > 0.f) ? (mx / 127.0f) : 1.0f;

#pragma unroll
    for (int c = 0; c < 4; ++c) {
      int qi[16];
#pragma unroll
      for (int j = 0; j < 4; ++j) {
        qi[j * 4 + 0] = __float2int_rn(v[c][j].x * inv);
        qi[j * 4 + 1] = __float2int_rn(v[c][j].y * inv);
        qi[j * 4 + 2] = __float2int_rn(v[c][j].z * inv);
        qi[j * 4 + 3] = __float2int_rn(v[c][j].w * inv);
      }
      int4 p;
      int* pp = (int*)&p;
#pragma unroll
      for (int w = 0; w < 4; ++w) {
        int a0 = min(127, max(-127, qi[w * 4 + 0])) & 0xff;
        int a1 = min(127, max(-127, qi[w * 4 + 1])) & 0xff;
        int a2 = min(127, max(-127, qi[w * 4 + 2])) & 0xff;
        int a3 = min(127, max(-127, qi[w * 4 + 3])) & 0xff;
        pp[w] = a0 | (a1 << 8) | (a2 << 16) | (a3 << 24);
      }
      *reinterpret_cast<int4*>(A8 + (size_t)row * K_IN + c * 1024 + lane * 16) = p;
    }
  } else {
    const int total = (N_OUT * K_IN) / 16;   // 1,048,576 units of 16 i8
    int idx = (blockIdx.x - M_TOK / 4) * blockDim.x + threadIdx.x;
    for (int i = idx; i < total; i += 2048 * 256) {
      int4 p;
      int* pp = (int*)&p;
#pragma unroll
      for (int w = 0; w < 4; ++w) {
        int4 s = reinterpret_cast<const int4*>(wq)[i * 4 + w];
        pp[w] = (s.x & 0xff) | ((s.y & 0xff) << 8) | ((s.z & 0xff) << 16) |
                ((s.w & 0xff) << 24);
      }
      reinterpret_cast<int4*>(B8)[i] = p;
    }
  }
}

// ---------------------------------------------------------------------------
// Pass 2: 256x256 8-phase i8 MFMA GEMM (round-3/round-5 verified structure,
// mfma_i32_16x16x64_i8, zero bank conflicts). MFMA order: kk-outer so
// adjacent MFMAs write different acc registers (no back-to-back dep chains).
// LDS 128 KiB: A(buf,h)=buf*65536+h*16384; B(buf,h)=+32768. 128-B rows =
// 8 slots of 16 B; phys_slot = log_slot ^ (row&7); linear LDS dest +
// inverse-swizzled global source (rule #21).
// ---------------------------------------------------------------------------
#define GLOAD_LDS16(gptr, lptr)                                               \
  __builtin_amdgcn_global_load_lds(                                           \
      (const __attribute__((address_space(1))) void*)(gptr),                  \
      (__attribute__((address_space(3))) void*)(lptr), 16, 0, 0)

#define WAITCNT(s) asm volatile("s_waitcnt " s ::: "memory")

#define LDSA(buf, mh, fm, kk)                                                 \
  (*reinterpret_cast<const i32x4*>(                                           \
      lds + (buf)*65536 + (mh)*16384 + aRow + (fm)*2048 +                     \
      (((((kk)*4) | sBase) ^ sXor) << 4)))
#define LDSB(buf, nh, fn, kk)                                                 \
  (*reinterpret_cast<const i32x4*>(                                           \
      lds + (buf)*65536 + 32768 + (nh)*16384 + bRow + (fn)*2048 +             \
      (((((kk)*4) | sBase) ^ sXor) << 4)))

#define STAGE_A(buf, h, kt)                                                   \
  do {                                                                        \
    const char* _s = stA + (size_t)(h) * 128 * K_IN + (kt) * BK;              \
    GLOAD_LDS16(_s, lds + (buf)*65536 + (h)*16384 + ldsW0);                   \
    GLOAD_LDS16(_s + (size_t)64 * K_IN,                                       \
                lds + (buf)*65536 + (h)*16384 + 8192 + ldsW0);                \
  } while (0)
#define STAGE_B(buf, h, kt)                                                   \
  do {                                                                        \
    const char* _s = stB + (size_t)(h) * 128 * K_IN + (kt) * BK;              \
    GLOAD_LDS16(_s, lds + (buf)*65536 + 32768 + (h)*16384 + ldsW0);           \
    GLOAD_LDS16(_s + (size_t)64 * K_IN,                                       \
                lds + (buf)*65536 + 32768 + (h)*16384 + 8192 + ldsW0);        \
  } while (0)

// kk-outer: 8 independent MFMAs per kk group (dep chains length 2, spaced 8)
#define MFMA16(mh, nh, BR)                                                    \
  do {                                                                        \
    _Pragma("unroll") for (int kk = 0; kk < 2; ++kk)                          \
    _Pragma("unroll") for (int fm = 0; fm < 4; ++fm)                          \
    _Pragma("unroll") for (int fn = 0; fn < 2; ++fn)                          \
      acc[mh][nh][fm][fn] = __builtin_amdgcn_mfma_i32_16x16x64_i8(            \
          aR[fm][kk], BR[fn][kk], acc[mh][nh][fm][fn], 0, 0, 0);              \
  } while (0)

#define PH_MID()                                                              \
  __builtin_amdgcn_s_barrier();                                               \
  WAITCNT("lgkmcnt(0)");                                                      \
  __builtin_amdgcn_sched_barrier(0);                                          \
  __builtin_amdgcn_s_setprio(1)

#define PH_END()                                                              \
  __builtin_amdgcn_s_setprio(0);                                              \
  __builtin_amdgcn_s_barrier();                                               \
  __builtin_amdgcn_sched_barrier(0)

#define PH_END_VM()                                                           \
  __builtin_amdgcn_s_setprio(0);                                              \
  WAITCNT("vmcnt(6)");                                                        \
  __builtin_amdgcn_sched_barrier(0);                                          \
  __builtin_amdgcn_s_barrier();                                               \
  __builtin_amdgcn_sched_barrier(0)

__global__ __launch_bounds__(512, 2) void gemm_8ph_i8(
    const char* __restrict__ A,        // [M][K] i8
    const char* __restrict__ B,        // [N][K] i8
    const float* __restrict__ sx,      // [M] per-row x scales
    const float* __restrict__ scales,  // [N]
    const float* __restrict__ bias,    // [N]
    float* __restrict__ out) {         // [M][N] f32
  __shared__ __align__(1024) char lds[131072];

  int bid = blockIdx.x;
  int swz = (bid & 7) * (512 / 8) + (bid >> 3);   // bijective, 512 % 8 == 0
  int bx = swz & 15;   // N tiles: 16
  int by = swz >> 4;   // M tiles: 32

  int tid = threadIdx.x;
  int lane = tid & 63;
  int wid = tid >> 6;
  int wm = wid >> 2;    // 0..1
  int wn = wid & 3;     // 0..3

  int aRow = (wm * 64 + (lane & 15)) * 128;   // bytes within A half
  int bRow = (wn * 32 + (lane & 15)) * 128;   // bytes within B half
  int sBase = lane >> 4;                      // 0..3
  int sXor = lane & 7;

  const char* stA = A + (size_t)(by * BM + wid * 8 + (lane >> 3)) * K_IN +
                    ((lane & 7) ^ (lane >> 3)) * 16;
  const char* stB = B + (size_t)(bx * BN + wid * 8 + (lane >> 3)) * K_IN +
                    ((lane & 7) ^ (lane >> 3)) * 16;
  int ldsW0 = wid * 1024;

  i32x4 acc[2][2][4][2] = {};   // [mh][nh][fm][fn], i32
  i32x4 aR[4][2];               // A frags [fm][kk]
  i32x4 bR0[2][2], bR1[2][2];   // B frags [fn][kk]

  // ---- prologue: tile0 (buf0) fully + 3 halves of tile1 (buf1) ----
  STAGE_A(0, 0, 0); STAGE_A(0, 1, 0); STAGE_B(0, 0, 0); STAGE_B(0, 1, 0);
  WAITCNT("vmcnt(4)");
  STAGE_A(1, 0, 1); STAGE_B(1, 0, 1); STAGE_B(1, 1, 1);
  WAITCNT("vmcnt(6)");
  __builtin_amdgcn_s_barrier();
  __builtin_amdgcn_sched_barrier(0);

#pragma unroll 1
  for (int it = 0; it < NIT; ++it) {
    int kt1 = 2 * it + 1;
    int kt2 = (2 * it + 2) & (NT - 1);
    int kt3 = (2 * it + 3) & (NT - 1);

    // P1: tile t (m0,n0); stage t+1 A-h1 -> buf1
#pragma unroll
    for (int fm = 0; fm < 4; ++fm) { aR[fm][0] = LDSA(0, 0, fm, 0); aR[fm][1] = LDSA(0, 0, fm, 1); }
#pragma unroll
    for (int fn = 0; fn < 2; ++fn) { bR0[fn][0] = LDSB(0, 0, fn, 0); bR0[fn][1] = LDSB(0, 0, fn, 1); }
    STAGE_A(1, 1, kt1);
    WAITCNT("lgkmcnt(8)");
    PH_MID();
    MFMA16(0, 0, bR0);
    PH_END();

    // P2: tile t (m0,n1); stage t+2 A-h0 -> buf0
#pragma unroll
    for (int fn = 0; fn < 2; ++fn) { bR1[fn][0] = LDSB(0, 1, fn, 0); bR1[fn][1] = LDSB(0, 1, fn, 1); }
    STAGE_A(0, 0, kt2);
    PH_MID();
    MFMA16(0, 1, bR1);
    PH_END();

    // P3: tile t (m1,n1); stage t+2 B-h0 -> buf0
#pragma unroll
    for (int fm = 0; fm < 4; ++fm) { aR[fm][0] = LDSA(0, 1, fm, 0); aR[fm][1] = LDSA(0, 1, fm, 1); }
    STAGE_B(0, 0, kt2);
    PH_MID();
    MFMA16(1, 1, bR1);
    PH_END();

    // P4: tile t (m1,n0); stage t+2 B-h1 -> buf0; vmcnt(6)
    STAGE_B(0, 1, kt2);
    PH_MID();
    MFMA16(1, 0, bR0);
    PH_END_VM();

    // P5: tile t+1 (m0,n0); stage t+2 A-h1 -> buf0
#pragma unroll
    for (int fm = 0; fm < 4; ++fm) { aR[fm][0] = LDSA(1, 0, fm, 0); aR[fm][1] = LDSA(1, 0, fm, 1); }
#pragma unroll
    for (int fn = 0; fn < 2; ++fn) { bR0[fn][0] = LDSB(1, 0, fn, 0); bR0[fn][1] = LDSB(1, 0, fn, 1); }
    STAGE_A(0, 1, kt2);
    WAITCNT("lgkmcnt(8)");
    PH_MID();
    MFMA16(0, 0, bR0);
    PH_END();

    // P6: tile t+1 (m0,n1); stage t+3 A-h0 -> buf1
#pragma unroll
    for (int fn = 0; fn < 2; ++fn) { bR1[fn][0] = LDSB(1, 1, fn, 0); bR1[fn][1] = LDSB(1, 1, fn, 1); }
    STAGE_A(1, 0, kt3);
    PH_MID();
    MFMA16(0, 1, bR1);
    PH_END();

    // P7: tile t+1 (m1,n1); stage t+3 B-h0 -> buf1
#pragma unroll
    for (int fm = 0; fm < 4; ++fm) { aR[fm][0] = LDSA(1, 1, fm, 0); aR[fm][1] = LDSA(1, 1, fm, 1); }
    STAGE_B(1, 0, kt3);
    PH_MID();
    MFMA16(1, 1, bR1);
    PH_END();

    // P8: tile t+1 (m1,n0); stage t+3 B-h1 -> buf1; vmcnt(6)
    STAGE_B(1, 1, kt3);
    PH_MID();
    MFMA16(1, 0, bR0);
    PH_END_VM();
  }

  // ---- epilogue: out = acc * (sx[row] * scales[col]) + bias[col] ----
  // C/D (shape-determined): col = lane&15, row = (lane>>4)*4 + reg
  float sxv[2][4][4];
#pragma unroll
  for (int mh = 0; mh < 2; ++mh)
#pragma unroll
    for (int fm = 0; fm < 4; ++fm) {
      int row0 = by * BM + mh * 128 + wm * 64 + fm * 16 + (lane >> 4) * 4;
#pragma unroll
      for (int r = 0; r < 4; ++r) sxv[mh][fm][r] = sx[row0 + r];
    }

#pragma unroll
  for (int nh = 0; nh < 2; ++nh)
#pragma unroll
    for (int fn = 0; fn < 2; ++fn) {
      int col = bx * BN + nh * 128 + wn * 32 + fn * 16 + (lane & 15);
      float so = scales[col];
      float bv = bias[col];
#pragma unroll
      for (int mh = 0; mh < 2; ++mh)
#pragma unroll
        for (int fm = 0; fm < 4; ++fm) {
          int row0 = by * BM + mh * 128 + wm * 64 + fm * 16 + (lane >> 4) * 4;
          i32x4 v = acc[mh][nh][fm][fn];
#pragma unroll
          for (int r = 0; r < 4; ++r)
            out[(size_t)(row0 + r) * N_OUT + col] =
                (float)v[r] * (sxv[mh][fm][r] * so) + bv;
        }
    }
}

// ---------------------------------------------------------------------------
// Fallback (tiny ws): simple fp32 LDS-tiled GEMM (correct, slow).
// ---------------------------------------------------------------------------
__global__ void fallback_gemm(const float* __restrict__ x,
                              const int* __restrict__ wq,
                              const float* __restrict__ scales,
                              const float* __restrict__ bias,
                              float* __restrict__ out) {
  __shared__ float xs[64][33];
  __shared__ float ws_[64][33];
  int tx = threadIdx.x & 15;
  int ty = threadIdx.x >> 4;
  int brow = blockIdx.y * 64, bcol = blockIdx.x * 64;
  float acc[4][4] = {};
  for (int k0 = 0; k0 < K_IN; k0 += 32) {
    for (int i = threadIdx.x; i < 64 * 32; i += 256) {
      int r = i >> 5, c = i & 31;
      xs[r][c] = x[(size_t)(brow + r) * K_IN + k0 + c];
      ws_[r][c] = (float)wq[(size_t)(bcol + r) * K_IN + k0 + c];
    }
    __syncthreads();
#pragma unroll 8
    for (int k = 0; k < 32; ++k) {
      float xv[4], wv[4];
#pragma unroll
      for (int i = 0; i < 4; ++i) xv[i] = xs[ty * 4 + i][k];
#pragma unroll
      for (int j = 0; j < 4; ++j) wv[j] = ws_[tx * 4 + j][k];
#pragma unroll
      for (int i = 0; i < 4; ++i)
#pragma unroll
        for (int j = 0; j < 4; ++j) acc[i][j] += xv[i] * wv[j];
    }
    __syncthreads();
  }
#pragma unroll
  for (int i = 0; i < 4; ++i)
#pragma unroll
    for (int j = 0; j < 4; ++j) {
      int o = bcol + tx * 4 + j;
      out[(size_t)(brow + ty * 4 + i) * N_OUT + o] = acc[i][j] * scales[o] + bias[o];
    }
}

extern "C" void kernel_launch(void* const* d_in, const int* in_sizes, int n_in,
                              void* d_out, int out_size, void* d_ws, size_t ws_size,
                              hipStream_t stream) {
  const float* x = (const float*)d_in[0];
  const int* wq = (const int*)d_in[1];
  const float* scales = (const float*)d_in[2];
  const float* bias = (const float*)d_in[3];
  float* out = (float*)d_out;

  const size_t offB = (size_t)M_TOK * K_IN;            // 32 MiB (A8)
  const size_t offS = offB + (size_t)N_OUT * K_IN;     // +16 MiB (B8)
  const size_t need = offS + (size_t)M_TOK * 4;        // +32 KiB (sx)

  if (ws_size >= need) {
    char* A8 = (char*)d_ws;
    char* B8 = (char*)d_ws + offB;
    float* sx = (float*)((char*)d_ws + offS);
    prep_kernel<<<M_TOK / 4 + 2048, 256, 0, stream>>>(x, wq, A8, sx, B8);
    gemm_8ph_i8<<<(M_TOK / BM) * (N_OUT / BN), 512, 0, stream>>>(
        A8, B8, sx, scales, bias, out);
  } else {
    dim3 grid(N_OUT / 64, M_TOK / 64);
    fallback_gemm<<<grid, 256, 0, stream>>>(x, wq, scales, bias, out);
  }
}

// Round 8
// 182.927 us; speedup vs baseline: 1.0303x; 1.0080x over previous
//
#include <hip/hip_runtime.h>
#include <stdint.h>

#define M_TOK 8192
#define N_OUT 4096
#define K_IN  4096

#define BM 256
#define BN 256
#define BK 128                 // bytes == elements (i8)
#define NT (K_IN / BK)         // 32 K-tiles
#define NIT (NT / 2)           // 16 iterations, 2 K-tiles each

typedef __attribute__((ext_vector_type(4))) int i32x4;

// ---------------------------------------------------------------------------
// Pass 1 (fused): blocks [0, 2048): per-token symmetric quant of x -> i8 + sx.
//                 blocks [2048, 4096): pack weight_q (i32) -> i8 (exact).
// ---------------------------------------------------------------------------
__global__ void prep_kernel(const float* __restrict__ x,
                            const int* __restrict__ wq,
                            char* __restrict__ A8,
                            float* __restrict__ sx,
                            char* __restrict__ B8) {
  if (blockIdx.x < M_TOK / 4) {
    int row = blockIdx.x * 4 + (threadIdx.x >> 6);
    int lane = threadIdx.x & 63;
    const float* xr = x + (size_t)row * K_IN;

    float4 v[4][4];
    float mx = 0.f;
#pragma unroll
    for (int c = 0; c < 4; ++c) {
      int base = c * 1024 + lane * 16;
#pragma unroll
      for (int j = 0; j < 4; ++j) {
        v[c][j] = *reinterpret_cast<const float4*>(xr + base + j * 4);
        mx = fmaxf(mx, fmaxf(fmaxf(fabsf(v[c][j].x), fabsf(v[c][j].y)),
                             fmaxf(fabsf(v[c][j].z), fabsf(v[c][j].w))));
      }
    }
#pragma unroll
    for (int m = 32; m > 0; m >>= 1) mx = fmaxf(mx, __shfl_xor(mx, m));

    float inv = (mx > 0.f) ? (127.0f / mx) : 0.f;
    if (lane == 0) sx[row] = (mx > 0.f) ? (mx / 127.0f) : 1.0f;

#pragma unroll
    for (int c = 0; c < 4; ++c) {
      int qi[16];
#pragma unroll
      for (int j = 0; j < 4; ++j) {
        qi[j * 4 + 0] = __float2int_rn(v[c][j].x * inv);
        qi[j * 4 + 1] = __float2int_rn(v[c][j].y * inv);
        qi[j * 4 + 2] = __float2int_rn(v[c][j].z * inv);
        qi[j * 4 + 3] = __float2int_rn(v[c][j].w * inv);
      }
      int4 p;
      int* pp = (int*)&p;
#pragma unroll
      for (int w = 0; w < 4; ++w) {
        int a0 = min(127, max(-127, qi[w * 4 + 0])) & 0xff;
        int a1 = min(127, max(-127, qi[w * 4 + 1])) & 0xff;
        int a2 = min(127, max(-127, qi[w * 4 + 2])) & 0xff;
        int a3 = min(127, max(-127, qi[w * 4 + 3])) & 0xff;
        pp[w] = a0 | (a1 << 8) | (a2 << 16) | (a3 << 24);
      }
      *reinterpret_cast<int4*>(A8 + (size_t)row * K_IN + c * 1024 + lane * 16) = p;
    }
  } else {
    const int total = (N_OUT * K_IN) / 16;   // 1,048,576 units of 16 i8
    int idx = (blockIdx.x - M_TOK / 4) * blockDim.x + threadIdx.x;
    for (int i = idx; i < total; i += 2048 * 256) {
      int4 p;
      int* pp = (int*)&p;
#pragma unroll
      for (int w = 0; w < 4; ++w) {
        int4 s = reinterpret_cast<const int4*>(wq)[i * 4 + w];
        pp[w] = (s.x & 0xff) | ((s.y & 0xff) << 8) | ((s.z & 0xff) << 16) |
                ((s.w & 0xff) << 24);
      }
      reinterpret_cast<int4*>(B8)[i] = p;
    }
  }
}

// ---------------------------------------------------------------------------
// Pass 2: 256x256 8-phase i8 MFMA GEMM (round-3/5/7 verified structure,
// mfma_i32_16x16x64_i8, zero bank conflicts).
// XCD swizzle: each XCD owns an 8x8 (by x bx) rectangle -> concurrent
// working set ~12 MB/XCD (was 4x16 -> ~18 MB): better L2/L3 locality for
// staging loads. Bijective: xcd = (by>>3)|((bx>>3)<<2), i = ((by&7)<<3)|(bx&7).
// LDS 128 KiB: A(buf,h)=buf*65536+h*16384; B(buf,h)=+32768. 128-B rows =
// 8 slots of 16 B; phys_slot = log_slot ^ (row&7); linear LDS dest +
// inverse-swizzled global source (rule #21).
// ---------------------------------------------------------------------------
#define GLOAD_LDS16(gptr, lptr)                                               \
  __builtin_amdgcn_global_load_lds(                                           \
      (const __attribute__((address_space(1))) void*)(gptr),                  \
      (__attribute__((address_space(3))) void*)(lptr), 16, 0, 0)

#define WAITCNT(s) asm volatile("s_waitcnt " s ::: "memory")

#define LDSA(buf, mh, fm, kk)                                                 \
  (*reinterpret_cast<const i32x4*>(                                           \
      lds + (buf)*65536 + (mh)*16384 + aRow + (fm)*2048 +                     \
      (((((kk)*4) | sBase) ^ sXor) << 4)))
#define LDSB(buf, nh, fn, kk)                                                 \
  (*reinterpret_cast<const i32x4*>(                                           \
      lds + (buf)*65536 + 32768 + (nh)*16384 + bRow + (fn)*2048 +             \
      (((((kk)*4) | sBase) ^ sXor) << 4)))

#define STAGE_A(buf, h, kt)                                                   \
  do {                                                                        \
    const char* _s = stA + (size_t)(h) * 128 * K_IN + (kt) * BK;              \
    GLOAD_LDS16(_s, lds + (buf)*65536 + (h)*16384 + ldsW0);                   \
    GLOAD_LDS16(_s + (size_t)64 * K_IN,                                       \
                lds + (buf)*65536 + (h)*16384 + 8192 + ldsW0);                \
  } while (0)
#define STAGE_B(buf, h, kt)                                                   \
  do {                                                                        \
    const char* _s = stB + (size_t)(h) * 128 * K_IN + (kt) * BK;              \
    GLOAD_LDS16(_s, lds + (buf)*65536 + 32768 + (h)*16384 + ldsW0);           \
    GLOAD_LDS16(_s + (size_t)64 * K_IN,                                       \
                lds + (buf)*65536 + 32768 + (h)*16384 + 8192 + ldsW0);        \
  } while (0)

// kk-outer: 8 independent MFMAs per kk group (dep chains length 2, spaced 8)
#define MFMA16(mh, nh, BR)                                                    \
  do {                                                                        \
    _Pragma("unroll") for (int kk = 0; kk < 2; ++kk)                          \
    _Pragma("unroll") for (int fm = 0; fm < 4; ++fm)                          \
    _Pragma("unroll") for (int fn = 0; fn < 2; ++fn)                          \
      acc[mh][nh][fm][fn] = __builtin_amdgcn_mfma_i32_16x16x64_i8(            \
          aR[fm][kk], BR[fn][kk], acc[mh][nh][fm][fn], 0, 0, 0);              \
  } while (0)

#define PH_MID()                                                              \
  __builtin_amdgcn_s_barrier();                                               \
  WAITCNT("lgkmcnt(0)");                                                      \
  __builtin_amdgcn_sched_barrier(0);                                          \
  __builtin_amdgcn_s_setprio(1)

#define PH_END()                                                              \
  __builtin_amdgcn_s_setprio(0);                                              \
  __builtin_amdgcn_s_barrier();                                               \
  __builtin_amdgcn_sched_barrier(0)

#define PH_END_VM()                                                           \
  __builtin_amdgcn_s_setprio(0);                                              \
  WAITCNT("vmcnt(6)");                                                        \
  __builtin_amdgcn_sched_barrier(0);                                          \
  __builtin_amdgcn_s_barrier();                                               \
  __builtin_amdgcn_sched_barrier(0)

__global__ __launch_bounds__(512, 2) void gemm_8ph_i8(
    const char* __restrict__ A,        // [M][K] i8
    const char* __restrict__ B,        // [N][K] i8
    const float* __restrict__ sx,      // [M] per-row x scales
    const float* __restrict__ scales,  // [N]
    const float* __restrict__ bias,    // [N]
    float* __restrict__ out) {         // [M][N] f32
  __shared__ __align__(1024) char lds[131072];

  // 8x8-per-XCD bijective swizzle (512 blocks = 8 XCDs x 64)
  int bid = blockIdx.x;
  int xcd = bid & 7;
  int i = bid >> 3;                    // 0..63 within XCD
  int by = (xcd & 3) * 8 + (i >> 3);   // 0..31  (M tiles)
  int bx = (xcd >> 2) * 8 + (i & 7);   // 0..15  (N tiles)

  int tid = threadIdx.x;
  int lane = tid & 63;
  int wid = tid >> 6;
  int wm = wid >> 2;    // 0..1
  int wn = wid & 3;     // 0..3

  int aRow = (wm * 64 + (lane & 15)) * 128;   // bytes within A half
  int bRow = (wn * 32 + (lane & 15)) * 128;   // bytes within B half
  int sBase = lane >> 4;                      // 0..3
  int sXor = lane & 7;

  const char* stA = A + (size_t)(by * BM + wid * 8 + (lane >> 3)) * K_IN +
                    ((lane & 7) ^ (lane >> 3)) * 16;
  const char* stB = B + (size_t)(bx * BN + wid * 8 + (lane >> 3)) * K_IN +
                    ((lane & 7) ^ (lane >> 3)) * 16;
  int ldsW0 = wid * 1024;

  i32x4 acc[2][2][4][2] = {};   // [mh][nh][fm][fn], i32
  i32x4 aR[4][2];               // A frags [fm][kk]
  i32x4 bR0[2][2], bR1[2][2];   // B frags [fn][kk]

  // ---- prologue: tile0 (buf0) fully + 3 halves of tile1 (buf1) ----
  STAGE_A(0, 0, 0); STAGE_A(0, 1, 0); STAGE_B(0, 0, 0); STAGE_B(0, 1, 0);
  WAITCNT("vmcnt(4)");
  STAGE_A(1, 0, 1); STAGE_B(1, 0, 1); STAGE_B(1, 1, 1);
  WAITCNT("vmcnt(6)");
  __builtin_amdgcn_s_barrier();
  __builtin_amdgcn_sched_barrier(0);

#pragma unroll 1
  for (int it = 0; it < NIT; ++it) {
    int kt1 = 2 * it + 1;
    int kt2 = (2 * it + 2) & (NT - 1);
    int kt3 = (2 * it + 3) & (NT - 1);

    // P1: tile t (m0,n0); stage t+1 A-h1 -> buf1
#pragma unroll
    for (int fm = 0; fm < 4; ++fm) { aR[fm][0] = LDSA(0, 0, fm, 0); aR[fm][1] = LDSA(0, 0, fm, 1); }
#pragma unroll
    for (int fn = 0; fn < 2; ++fn) { bR0[fn][0] = LDSB(0, 0, fn, 0); bR0[fn][1] = LDSB(0, 0, fn, 1); }
    STAGE_A(1, 1, kt1);
    WAITCNT("lgkmcnt(8)");
    PH_MID();
    MFMA16(0, 0, bR0);
    PH_END();

    // P2: tile t (m0,n1); stage t+2 A-h0 -> buf0
#pragma unroll
    for (int fn = 0; fn < 2; ++fn) { bR1[fn][0] = LDSB(0, 1, fn, 0); bR1[fn][1] = LDSB(0, 1, fn, 1); }
    STAGE_A(0, 0, kt2);
    PH_MID();
    MFMA16(0, 1, bR1);
    PH_END();

    // P3: tile t (m1,n1); stage t+2 B-h0 -> buf0
#pragma unroll
    for (int fm = 0; fm < 4; ++fm) { aR[fm][0] = LDSA(0, 1, fm, 0); aR[fm][1] = LDSA(0, 1, fm, 1); }
    STAGE_B(0, 0, kt2);
    PH_MID();
    MFMA16(1, 1, bR1);
    PH_END();

    // P4: tile t (m1,n0); stage t+2 B-h1 -> buf0; vmcnt(6)
    STAGE_B(0, 1, kt2);
    PH_MID();
    MFMA16(1, 0, bR0);
    PH_END_VM();

    // P5: tile t+1 (m0,n0); stage t+2 A-h1 -> buf0
#pragma unroll
    for (int fm = 0; fm < 4; ++fm) { aR[fm][0] = LDSA(1, 0, fm, 0); aR[fm][1] = LDSA(1, 0, fm, 1); }
#pragma unroll
    for (int fn = 0; fn < 2; ++fn) { bR0[fn][0] = LDSB(1, 0, fn, 0); bR0[fn][1] = LDSB(1, 0, fn, 1); }
    STAGE_A(0, 1, kt2);
    WAITCNT("lgkmcnt(8)");
    PH_MID();
    MFMA16(0, 0, bR0);
    PH_END();

    // P6: tile t+1 (m0,n1); stage t+3 A-h0 -> buf1
#pragma unroll
    for (int fn = 0; fn < 2; ++fn) { bR1[fn][0] = LDSB(1, 1, fn, 0); bR1[fn][1] = LDSB(1, 1, fn, 1); }
    STAGE_A(1, 0, kt3);
    PH_MID();
    MFMA16(0, 1, bR1);
    PH_END();

    // P7: tile t+1 (m1,n1); stage t+3 B-h0 -> buf1
#pragma unroll
    for (int fm = 0; fm < 4; ++fm) { aR[fm][0] = LDSA(1, 1, fm, 0); aR[fm][1] = LDSA(1, 1, fm, 1); }
    STAGE_B(1, 0, kt3);
    PH_MID();
    MFMA16(1, 1, bR1);
    PH_END();

    // P8: tile t+1 (m1,n0); stage t+3 B-h1 -> buf1; vmcnt(6)
    STAGE_B(1, 1, kt3);
    PH_MID();
    MFMA16(1, 0, bR0);
    PH_END_VM();
  }

  // ---- epilogue: out = acc * (sx[row] * scales[col]) + bias[col] ----
  // C/D (shape-determined): col = lane&15, row = (lane>>4)*4 + reg
  float sxv[2][4][4];
#pragma unroll
  for (int mh = 0; mh < 2; ++mh)
#pragma unroll
    for (int fm = 0; fm < 4; ++fm) {
      int row0 = by * BM + mh * 128 + wm * 64 + fm * 16 + (lane >> 4) * 4;
#pragma unroll
      for (int r = 0; r < 4; ++r) sxv[mh][fm][r] = sx[row0 + r];
    }

#pragma unroll
  for (int nh = 0; nh < 2; ++nh)
#pragma unroll
    for (int fn = 0; fn < 2; ++fn) {
      int col = bx * BN + nh * 128 + wn * 32 + fn * 16 + (lane & 15);
      float so = scales[col];
      float bv = bias[col];
#pragma unroll
      for (int mh = 0; mh < 2; ++mh)
#pragma unroll
        for (int fm = 0; fm < 4; ++fm) {
          int row0 = by * BM + mh * 128 + wm * 64 + fm * 16 + (lane >> 4) * 4;
          i32x4 v = acc[mh][nh][fm][fn];
#pragma unroll
          for (int r = 0; r < 4; ++r)
            out[(size_t)(row0 + r) * N_OUT + col] =
                (float)v[r] * (sxv[mh][fm][r] * so) + bv;
        }
    }
}

// ---------------------------------------------------------------------------
// Fallback (tiny ws): simple fp32 LDS-tiled GEMM (correct, slow).
// ---------------------------------------------------------------------------
__global__ void fallback_gemm(const float* __restrict__ x,
                              const int* __restrict__ wq,
                              const float* __restrict__ scales,
                              const float* __restrict__ bias,
                              float* __restrict__ out) {
  __shared__ float xs[64][33];
  __shared__ float ws_[64][33];
  int tx = threadIdx.x & 15;
  int ty = threadIdx.x >> 4;
  int brow = blockIdx.y * 64, bcol = blockIdx.x * 64;
  float acc[4][4] = {};
  for (int k0 = 0; k0 < K_IN; k0 += 32) {
    for (int i = threadIdx.x; i < 64 * 32; i += 256) {
      int r = i >> 5, c = i & 31;
      xs[r][c] = x[(size_t)(brow + r) * K_IN + k0 + c];
      ws_[r][c] = (float)wq[(size_t)(bcol + r) * K_IN + k0 + c];
    }
    __syncthreads();
#pragma unroll 8
    for (int k = 0; k < 32; ++k) {
      float xv[4], wv[4];
#pragma unroll
      for (int i = 0; i < 4; ++i) xv[i] = xs[ty * 4 + i][k];
#pragma unroll
      for (int j = 0; j < 4; ++j) wv[j] = ws_[tx * 4 + j][k];
#pragma unroll
      for (int i = 0; i < 4; ++i)
#pragma unroll
        for (int j = 0; j < 4; ++j) acc[i][j] += xv[i] * wv[j];
    }
    __syncthreads();
  }
#pragma unroll
  for (int i = 0; i < 4; ++i)
#pragma unroll
    for (int j = 0; j < 4; ++j) {
      int o = bcol + tx * 4 + j;
      out[(size_t)(brow + ty * 4 + i) * N_OUT + o] = acc[i][j] * scales[o] + bias[o];
    }
}

extern "C" void kernel_launch(void* const* d_in, const int* in_sizes, int n_in,
                              void* d_out, int out_size, void* d_ws, size_t ws_size,
                              hipStream_t stream) {
  const float* x = (const float*)d_in[0];
  const int* wq = (const int*)d_in[1];
  const float* scales = (const float*)d_in[2];
  const float* bias = (const float*)d_in[3];
  float* out = (float*)d_out;

  const size_t offB = (size_t)M_TOK * K_IN;            // 32 MiB (A8)
  const size_t offS = offB + (size_t)N_OUT * K_IN;     // +16 MiB (B8)
  const size_t need = offS + (size_t)M_TOK * 4;        // +32 KiB (sx)

  if (ws_size >= need) {
    char* A8 = (char*)d_ws;
    char* B8 = (char*)d_ws + offB;
    float* sx = (float*)((char*)d_ws + offS);
    prep_kernel<<<M_TOK / 4 + 2048, 256, 0, stream>>>(x, wq, A8, sx, B8);
    gemm_8ph_i8<<<(M_TOK / BM) * (N_OUT / BN), 512, 0, stream>>>(
        A8, B8, sx, scales, bias, out);
  } else {
    dim3 grid(N_OUT / 64, M_TOK / 64);
    fallback_gemm<<<grid, 256, 0, stream>>>(x, wq, scales, bias, out);
  }
}